// Round 3
// baseline (316.517 us; speedup 1.0000x reference)
//
#include <hip/hip_runtime.h>

typedef __bf16 bf16x8 __attribute__((ext_vector_type(8)));
typedef float f32x4 __attribute__((ext_vector_type(4)));

// ---------------- minifloat quantize (e4m3-style: E=4, M=3, bias=7) ----------------
// grid: emin=-6, emax=7, max=240. floor(log2|t|) == fp32 exponent field (normals);
// zeros/denormals fall into the clamped-subnormal path and round to 0 exactly as ref.
__device__ __forceinline__ float quant1(float t) {
    unsigned bits = __float_as_uint(t);
    int eb = (int)((bits & 0x7fffffffu) >> 23);   // biased exponent of |t|
    eb = eb < 121 ? 121 : eb;                     // clamp: e >= -6  (121 = -6+127)
    float m = __uint_as_float((unsigned)(257 - eb) << 23);  // 2^(3-e)
    float s = __uint_as_float((unsigned)(eb - 3) << 23);    // 2^(e-3)
    float q = rintf(t * m) * s;                   // RNE, matches np.round
    q = fminf(q, 240.0f);
    q = fmaxf(q, -240.0f);
    return q;
}

// exact: quantized values have <=4 significand bits, bf16 has 8
__device__ __forceinline__ unsigned short bf16bits(float f) {
    return (unsigned short)(__float_as_uint(f) >> 16);
}

// ---------------- quantize kernels ----------------
__global__ void quant8_bf16_kernel(const float* __restrict__ in,
                                   unsigned short* __restrict__ out, long long n8) {
    long long i = (long long)blockIdx.x * blockDim.x + threadIdx.x;
    if (i >= n8) return;
    const float4* p = (const float4*)in;
    float4 a = p[2 * i], b = p[2 * i + 1];
    union { unsigned short u[8]; uint4 v; } o;
    o.u[0] = bf16bits(quant1(a.x));
    o.u[1] = bf16bits(quant1(a.y));
    o.u[2] = bf16bits(quant1(a.z));
    o.u[3] = bf16bits(quant1(a.w));
    o.u[4] = bf16bits(quant1(b.x));
    o.u[5] = bf16bits(quant1(b.y));
    o.u[6] = bf16bits(quant1(b.z));
    o.u[7] = bf16bits(quant1(b.w));
    ((uint4*)out)[i] = o.v;
}

__global__ void quant_f32_kernel(const float* __restrict__ in,
                                 float* __restrict__ out, int n) {
    int i = blockIdx.x * blockDim.x + threadIdx.x;
    if (i < n) out[i] = quant1(in[i]);
}

// ---------------- bf16 MFMA GEMM: C[M,N] = A[M,K] * B[N,K]^T + bias ----------------
#define BM 128
#define BN 128
#define BK 32

__device__ __forceinline__ void gload_lds16(const void* g, void* l) {
    __builtin_amdgcn_global_load_lds(
        (const __attribute__((address_space(1))) void*)g,
        (__attribute__((address_space(3))) void*)l, 16, 0, 0);
}

__global__ __launch_bounds__(256, 2) void gemm_bf16q_kernel(
    const unsigned short* __restrict__ A,   // [M,K] bf16 bits
    const unsigned short* __restrict__ B,   // [N,K] bf16 bits (w layout)
    const float* __restrict__ bias,         // [N] quantized bias
    float* __restrict__ C, int M, int N, int K)
{
    __shared__ __align__(16) unsigned short As[BM * BK];  // 8 KB
    __shared__ __align__(16) unsigned short Bs[BN * BK];  // 8 KB

    const int t    = threadIdx.x;
    const int lane = t & 63;
    const int wid  = t >> 6;           // 4 waves: 2x2
    const int wm   = (wid >> 1) * 64;  // wave row offset in tile
    const int wn   = (wid & 1) * 64;   // wave col offset in tile
    const int fr   = lane & 15;        // fragment row/col index
    const int kg   = lane >> 4;        // k-group 0..3

    const int rowA0 = blockIdx.x * BM;
    const int colB0 = blockIdx.y * BN;

    f32x4 acc[4][4] = {};

    const int c0 = t;          // staging chunk ids (16B each, 512 chunks per tile)
    const int c1 = t + 256;

    for (int kt = 0; kt < K; kt += BK) {
        // ---- stage A & B tiles: global -> LDS, 16B per lane, wave-linear dest ----
        {
            const unsigned short* ga0 = A + (size_t)(rowA0 + (c0 >> 2)) * K + kt + (c0 & 3) * 8;
            gload_lds16(ga0, &As[c0 * 8]);
            const unsigned short* ga1 = A + (size_t)(rowA0 + (c1 >> 2)) * K + kt + (c1 & 3) * 8;
            gload_lds16(ga1, &As[c1 * 8]);
            const unsigned short* gb0 = B + (size_t)(colB0 + (c0 >> 2)) * K + kt + (c0 & 3) * 8;
            gload_lds16(gb0, &Bs[c0 * 8]);
            const unsigned short* gb1 = B + (size_t)(colB0 + (c1 >> 2)) * K + kt + (c1 & 3) * 8;
            gload_lds16(gb1, &Bs[c1 * 8]);
        }
        __syncthreads();   // compiler drains vmcnt before barrier

        bf16x8 af[4], bfm[4];
        #pragma unroll
        for (int m = 0; m < 4; ++m)
            af[m] = *(const bf16x8*)&As[(wm + m * 16 + fr) * BK + kg * 8];
        #pragma unroll
        for (int n = 0; n < 4; ++n)
            bfm[n] = *(const bf16x8*)&Bs[(wn + n * 16 + fr) * BK + kg * 8];

        #pragma unroll
        for (int m = 0; m < 4; ++m)
            #pragma unroll
            for (int n = 0; n < 4; ++n)
                acc[m][n] = __builtin_amdgcn_mfma_f32_16x16x32_bf16(
                    af[m], bfm[n], acc[m][n], 0, 0, 0);

        __syncthreads();
    }

    // ---- epilogue: C/D layout col=lane&15, row=(lane>>4)*4+reg ----
    #pragma unroll
    for (int m = 0; m < 4; ++m) {
        int row = rowA0 + wm + m * 16 + kg * 4;
        #pragma unroll
        for (int n = 0; n < 4; ++n) {
            int col = colB0 + wn + n * 16 + fr;
            float bb = bias[col];
            #pragma unroll
            for (int r = 0; r < 4; ++r)
                C[(size_t)(row + r) * N + col] = acc[m][n][r] + bb;
        }
    }
}

// ---------------- naive fallback (no workspace needed) ----------------
__global__ void naive_gemm_kernel(const float* __restrict__ x, const float* __restrict__ w,
                                  const float* __restrict__ b, float* __restrict__ out,
                                  int M, int N, int K) {
    int col = blockIdx.x * blockDim.x + threadIdx.x;
    int row = blockIdx.y;
    if (col >= N || row >= M) return;
    const float* xr = x + (size_t)row * K;
    const float* wr = w + (size_t)col * K;
    float acc = 0.f;
    for (int k = 0; k < K; ++k) acc += quant1(xr[k]) * quant1(wr[k]);
    out[(size_t)row * N + col] = acc + quant1(b[col]);
}

extern "C" void kernel_launch(void* const* d_in, const int* in_sizes, int n_in,
                              void* d_out, int out_size, void* d_ws, size_t ws_size,
                              hipStream_t stream) {
    const float* x = (const float*)d_in[0];
    const float* w = (const float*)d_in[1];
    const float* b = (const float*)d_in[2];
    float* out = (float*)d_out;

    const int xsz = in_sizes[0];
    const int wsz = in_sizes[1];
    const int N   = in_sizes[2];
    const int K   = wsz / N;
    const int M   = xsz / K;

    const size_t xq_bytes = (size_t)xsz * 2;
    const size_t wq_bytes = (size_t)wsz * 2;
    const size_t need = xq_bytes + wq_bytes + (size_t)N * 4;

    const bool fast_ok = (ws_size >= need) &&
                         (M % BM == 0) && (N % BN == 0) && (K % BK == 0) &&
                         (xsz % 8 == 0) && (wsz % 8 == 0);

    if (fast_ok) {
        unsigned short* xq = (unsigned short*)d_ws;
        unsigned short* wq = (unsigned short*)((char*)d_ws + xq_bytes);
        float*          bq = (float*)((char*)d_ws + xq_bytes + wq_bytes);

        long long n8x = xsz / 8;
        quant8_bf16_kernel<<<(int)((n8x + 255) / 256), 256, 0, stream>>>(x, xq, n8x);
        long long n8w = wsz / 8;
        quant8_bf16_kernel<<<(int)((n8w + 255) / 256), 256, 0, stream>>>(w, wq, n8w);
        quant_f32_kernel<<<(N + 255) / 256, 256, 0, stream>>>(b, bq, N);

        dim3 grid(M / BM, N / BN);
        gemm_bf16q_kernel<<<grid, 256, 0, stream>>>(xq, wq, bq, out, M, N, K);
    } else {
        dim3 grid((N + 255) / 256, M);
        naive_gemm_kernel<<<grid, 256, 0, stream>>>(x, w, b, out, M, N, K);
    }
}